// Round 1
// baseline (173.409 us; speedup 1.0000x reference)
//
#include <hip/hip_runtime.h>

// out[b,o,hw] = sum_c W[o,c] * x[b,c,hw]
// x: (B, C, H, W) fp32 contiguous, C=256, H*W=3136 (784 float4, 16B-aligned).
// W: (C, C) fp32 (conv_weights[:, :, 0, 0]).
//
// R2 structure: one INDEPENDENT WAVE per output plane (b, o).
//   grid = B * C/4 blocks, 256 threads = 4 waves; wave wv owns row o = 4*og+wv.
//   - Prologue: per-wave compaction of W[o,:] (f4-coalesced read, shfl_up
//     prefix sum) into this wave's private LDS slice. NO __syncthreads
//     anywhere: same-wave LDS RAW needs only lgkmcnt, which the compiler
//     inserts. Pruned-row waves (nnz=0) never gate live waves.
//   - Hot loop: per nonzero c, issue ALL 13 plane loads back-to-back
//     (12x full 64-lane f4 slots + 16-lane tail) -> 13 outstanding HBM
//     loads/lane, one dense contiguous 12.5 KB read burst per wave.
//   - Nontemporal loads/stores: pure streaming, keep L2 for W rows.

#define C_CH  256
#define HW    3136
#define HW4   784            // HW / 4
#define SLOTS 12             // full 64-lane f4 slots: 12*64 = 768
#define TAIL  (HW4 - SLOTS * 64)   // 16

typedef float f4 __attribute__((ext_vector_type(4)));

__global__ __launch_bounds__(256) void channel_mix_sparse(
    const float* __restrict__ x,
    const float* __restrict__ w,   // (C_CH, C_CH) row-major
    float* __restrict__ out) {
  __shared__ int   s_idx[4][C_CH];
  __shared__ float s_val[4][C_CH];

  const int tid  = threadIdx.x;
  const int wv   = tid >> 6;
  const int lane = tid & 63;
  const int b    = blockIdx.x >> 6;        // C_CH/4 = 64 o-groups per batch
  const int og   = blockIdx.x & 63;
  const int o    = og * 4 + wv;            // this wave's output row

  // ---- per-wave compaction of W[o,:] into (s_idx[wv], s_val[wv]) ----
  // Each lane holds 4 consecutive W entries (f4, 1 KB coalesced per wave).
  const f4 wrow = ((const f4*)(w + (size_t)o * C_CH))[lane];
  int cnt = 0;
#pragma unroll
  for (int j = 0; j < 4; ++j) cnt += (wrow[j] != 0.0f) ? 1 : 0;

  // Inclusive prefix sum over lanes via shfl_up butterfly.
  int off = cnt;
#pragma unroll
  for (int d = 1; d < 64; d <<= 1) {
    int t = __shfl_up(off, d);
    if (lane >= d) off += t;
  }
  const int nnz = __shfl(off, 63);  // total nonzeros of this row
  off -= cnt;                       // exclusive prefix = my write position

#pragma unroll
  for (int j = 0; j < 4; ++j) {
    if (wrow[j] != 0.0f) {
      s_idx[wv][off] = lane * 4 + j;
      s_val[wv][off] = wrow[j];
      ++off;
    }
  }
  // Same-wave LDS read-after-write: lgkmcnt wait only, no barrier needed.

  const f4* __restrict__ xb = (const f4*)(x + (size_t)b * C_CH * HW);
  f4* __restrict__ ob = (f4*)(out + ((size_t)b * C_CH + o) * HW);

  f4 acc[SLOTS];
#pragma unroll
  for (int s = 0; s < SLOTS; ++s) acc[s] = (f4)0.f;
  f4 accT = (f4)0.f;
  const bool hasT = (lane < TAIL);

  for (int k = 0; k < nnz; ++k) {
    const int   c = s_idx[wv][k];
    const float v = s_val[wv][k];
    const f4* __restrict__ src = xb + (size_t)c * HW4 + lane;
    f4 a[SLOTS];
#pragma unroll
    for (int s = 0; s < SLOTS; ++s)
      a[s] = __builtin_nontemporal_load(src + s * 64);
    f4 aT = hasT ? __builtin_nontemporal_load(src + SLOTS * 64) : (f4)0.f;
#pragma unroll
    for (int s = 0; s < SLOTS; ++s) acc[s] += a[s] * v;
    accT += aT * v;
  }

  f4* __restrict__ dst = ob + lane;
#pragma unroll
  for (int s = 0; s < SLOTS; ++s)
    __builtin_nontemporal_store(acc[s], dst + s * 64);
  if (hasT) __builtin_nontemporal_store(accT, dst + SLOTS * 64);
}

extern "C" void kernel_launch(void* const* d_in, const int* in_sizes, int n_in,
                              void* d_out, int out_size, void* d_ws, size_t ws_size,
                              hipStream_t stream) {
  const float* x = (const float*)d_in[0];
  const float* w = (const float*)d_in[1];   // (256, 256, 1, 1) -> (256, 256)
  float* out = (float*)d_out;

  const int B = in_sizes[0] / (C_CH * HW);  // 32

  dim3 grid(B * (C_CH / 4));                // one wave per (b, o) plane
  dim3 block(256);
  channel_mix_sparse<<<grid, block, 0, stream>>>(x, w, out);
}

// Round 2
// 171.312 us; speedup vs baseline: 1.0122x; 1.0122x over previous
//
#include <hip/hip_runtime.h>

// out[b,o,hw] = sum_c W[o,c] * x[b,c,hw]
// x: (B, C, H, W) fp32 contiguous, C=256, H*W=3136 (784 float4, 16B-aligned).
// W: (C, C) fp32 (conv_weights[:, :, 0, 0]).
//
// R3: break the W->x serial chain (theory: per-wave prologue latency is the
// ~40% duty-cycle loss common to R0/R1).
//   - One wave per (b, o) plane. grid = B * C/4 blocks x 256 threads.
//   - wdiag = W[o][o] fetched via wave-uniform SCALAR load at cycle 0
//     (L2-hot, ~150 cy) -> the 13 diagonal-plane x loads issue immediately,
//     gated only on wdiag, NOT on the vector W-row load or the compaction.
//   - Row compaction (shfl prefix + LDS, for arbitrary-W extras) executes
//     INSIDE the x-load latency window.
//   - Pruned rows (wdiag==0, nnz==0): no x reads, store zeros, retire fast.
//   - Extras loop (c != o) is the general-W path; never taken for the
//     bench's pruned-identity W. Chunked 4-slot loads, low VGPR.
//   - Nontemporal loads/stores: pure streaming, keep L2 for W.

#define C_CH  256
#define HW    3136
#define HW4   784            // HW / 4
#define SLOTS 12             // full 64-lane f4 slots: 12*64 = 768
#define TAIL  (HW4 - SLOTS * 64)   // 16

typedef float f4 __attribute__((ext_vector_type(4)));

__global__ __launch_bounds__(256) void channel_mix_sparse(
    const float* __restrict__ x,
    const float* __restrict__ w,   // (C_CH, C_CH) row-major
    float* __restrict__ out) {
  __shared__ int   s_idx[4][C_CH];
  __shared__ float s_val[4][C_CH];

  const int tid  = threadIdx.x;
  const int wv   = tid >> 6;
  const int lane = tid & 63;
  const int b    = blockIdx.x >> 6;        // 64 o-groups per batch
  const int og   = blockIdx.x & 63;
  const int o    = og * 4 + wv;            // this wave's output row

  // Wave-uniform diagonal weight via scalar path (o is uniform per wave;
  // readfirstlane nudges the compiler to prove it -> s_load).
  const int o_u = __builtin_amdgcn_readfirstlane(o);
  const float wdiag = w[(size_t)o_u * C_CH + o_u];

  // Full row (vector f4 load) for the general/extras path; issues
  // concurrently with the scalar load.
  const f4 wrow = ((const f4*)(w + (size_t)o_u * C_CH))[lane];

  const f4* __restrict__ xb  = (const f4*)(x + (size_t)b * C_CH * HW);
  f4* __restrict__ ob        = (f4*)(out + ((size_t)b * C_CH + o_u) * HW);
  const f4* __restrict__ src = xb + (size_t)o_u * HW4 + lane;  // diagonal plane

  const bool hasT = (lane < TAIL);

  // ---- speculative diagonal-plane stream: gated ONLY on wdiag ----
  f4 a[SLOTS]; f4 aT;
  if (wdiag != 0.0f) {
#pragma unroll
    for (int s = 0; s < SLOTS; ++s)
      a[s] = __builtin_nontemporal_load(src + s * 64);
    aT = hasT ? __builtin_nontemporal_load(src + SLOTS * 64) : (f4)0.f;
#pragma unroll
    for (int s = 0; s < SLOTS; ++s) a[s] *= wdiag;
    aT *= wdiag;
  } else {
#pragma unroll
    for (int s = 0; s < SLOTS; ++s) a[s] = (f4)0.f;
    aT = (f4)0.f;
  }

  // ---- row compaction (fills the load-latency window) ----
  int cnt = 0;
#pragma unroll
  for (int j = 0; j < 4; ++j) cnt += (wrow[j] != 0.0f) ? 1 : 0;
  int off = cnt;
#pragma unroll
  for (int d = 1; d < 64; d <<= 1) {
    int t = __shfl_up(off, d);
    if (lane >= d) off += t;
  }
  const int nnz = __shfl(off, 63);
  off -= cnt;
#pragma unroll
  for (int j = 0; j < 4; ++j) {
    if (wrow[j] != 0.0f) {
      s_idx[wv][off] = lane * 4 + j;
      s_val[wv][off] = wrow[j];
      ++off;
    }
  }
  // Same-wave LDS RAW: lgkmcnt only, no barrier.

  // ---- extras: nonzero columns other than the diagonal (general W) ----
  for (int k = 0; k < nnz; ++k) {
    const int c = s_idx[wv][k];
    if (c == o_u) continue;          // diagonal already applied via wdiag
    const float v = s_val[wv][k];
    const f4* __restrict__ s2 = xb + (size_t)c * HW4 + lane;
#pragma unroll
    for (int s0 = 0; s0 < SLOTS; s0 += 4) {
      f4 t0 = __builtin_nontemporal_load(s2 + (s0 + 0) * 64);
      f4 t1 = __builtin_nontemporal_load(s2 + (s0 + 1) * 64);
      f4 t2 = __builtin_nontemporal_load(s2 + (s0 + 2) * 64);
      f4 t3 = __builtin_nontemporal_load(s2 + (s0 + 3) * 64);
      a[s0 + 0] += t0 * v;
      a[s0 + 1] += t1 * v;
      a[s0 + 2] += t2 * v;
      a[s0 + 3] += t3 * v;
    }
    if (hasT) aT += __builtin_nontemporal_load(s2 + SLOTS * 64) * v;
  }

  // ---- store ----
  f4* __restrict__ dst = ob + lane;
#pragma unroll
  for (int s = 0; s < SLOTS; ++s)
    __builtin_nontemporal_store(a[s], dst + s * 64);
  if (hasT) __builtin_nontemporal_store(aT, dst + SLOTS * 64);
}

extern "C" void kernel_launch(void* const* d_in, const int* in_sizes, int n_in,
                              void* d_out, int out_size, void* d_ws, size_t ws_size,
                              hipStream_t stream) {
  const float* x = (const float*)d_in[0];
  const float* w = (const float*)d_in[1];   // (256, 256, 1, 1) -> (256, 256)
  float* out = (float*)d_out;

  const int B = in_sizes[0] / (C_CH * HW);  // 32

  dim3 grid(B * (C_CH / 4));                // one wave per (b, o) plane
  dim3 block(256);
  channel_mix_sparse<<<grid, block, 0, stream>>>(x, w, out);
}